// Round 4
// baseline (253.880 us; speedup 1.0000x reference)
//
#include <hip/hip_runtime.h>
#include <hip/hip_bf16.h>
#include <cstdint>

typedef unsigned short u16;
typedef __attribute__((ext_vector_type(8))) short short8;
typedef __attribute__((ext_vector_type(4))) float f32x4;
typedef __attribute__((ext_vector_type(4))) unsigned short us4;

__device__ __forceinline__ float bf2f(u16 u){union{unsigned i;float f;}v;v.i=(unsigned)u<<16;return v.f;}
__device__ __forceinline__ u16 f2bf(float f){union{float f;unsigned i;}v;v.f=f;unsigned x=v.i;unsigned r=x+0x7fffu+((x>>16)&1u);return (u16)(r>>16);}

enum { EPI_BF16=0, EPI_LMSM=1, EPI_HT=2, EPI_OUT=3 };

// C[M,N] = A[M,K] @ B[N,K]^T, K-contig operands, BK=64, 256 thr (2x2 waves).
// bf16 operands: global_load_lds(16B) with XOR-8 swizzle on the global chunk.
// f32 operands: float4 load -> cvt bf16 -> swizzled ds_write (same LDS layout).
template<int BM,int BN,bool AF32,bool BF32,int EPI>
__global__ void __launch_bounds__(256)
gemm(const void* __restrict__ Ap, const void* __restrict__ A2p,
     const void* __restrict__ Bp, void* __restrict__ Cp, void* __restrict__ C2p,
     float* __restrict__ auxF, const float* __restrict__ biasCol,
     const float* __restrict__ rinv,
     int M, int N, int K, long sA, long sB, long sC, float expScale)
{
    constexpr int MFRAG = BM/32;
    constexpr int NFRAG = BN/32;
    __shared__ alignas(16) u16 As[BM*64];
    __shared__ alignas(16) u16 Bs[BN*64];

    const int tid=threadIdx.x, lane=tid&63, quad=lane>>4, l15=lane&15;
    const int w=tid>>6, wm=w>>1, wn=w&1;
    const int z=blockIdx.z;
    const int m0=blockIdx.y*BM, n0=blockIdx.x*BN;

    const int r8=tid>>3, cl=tid&7, cg=((cl^(r8&7))*8);  // bf16 staging
    const int r16=tid>>4, q16=tid&15;                    // f32 staging
    const int sw=l15&7;

    const void* Abase = (A2p && z) ? A2p : Ap;
    const long zOffA = A2p ? 0 : (long)z*sA;
    const long zOffB = (long)z*sB;

    f32x4 acc[MFRAG][NFRAG] = {};

    for (int k0=0;k0<K;k0+=64){
        if constexpr (AF32){
            const float* S=(const float*)Abase+zOffA+(long)m0*K+k0;
#pragma unroll
            for (int j=0;j<BM/16;++j){
                int row=j*16+r16;
                float4 v=*(const float4*)(S+(long)row*K+q16*4);
                us4 o; o.x=f2bf(v.x);o.y=f2bf(v.y);o.z=f2bf(v.z);o.w=f2bf(v.w);
                *(us4*)&As[row*64+(((q16>>1)^(row&7))<<3)+((q16&1)<<2)]=o;
            }
        } else {
            const u16* S=(const u16*)Abase+zOffA+(long)m0*K+k0+cg;
#pragma unroll
            for (int j=0;j<BM/32;++j)
                __builtin_amdgcn_global_load_lds(
                    (const __attribute__((address_space(1))) void*)(S+(long)(j*32+r8)*K),
                    (__attribute__((address_space(3))) void*)(&As[(j*32+r8)*64+cl*8]),16,0,0);
        }
        if constexpr (BF32){
            const float* S=(const float*)Bp+zOffB+(long)n0*K+k0;
#pragma unroll
            for (int j=0;j<BN/16;++j){
                int row=j*16+r16;
                float4 v=*(const float4*)(S+(long)row*K+q16*4);
                us4 o; o.x=f2bf(v.x);o.y=f2bf(v.y);o.z=f2bf(v.z);o.w=f2bf(v.w);
                *(us4*)&Bs[row*64+(((q16>>1)^(row&7))<<3)+((q16&1)<<2)]=o;
            }
        } else {
            const u16* S=(const u16*)Bp+zOffB+(long)n0*K+k0+cg;
#pragma unroll
            for (int j=0;j<BN/32;++j)
                __builtin_amdgcn_global_load_lds(
                    (const __attribute__((address_space(1))) void*)(S+(long)(j*32+r8)*K),
                    (__attribute__((address_space(3))) void*)(&Bs[(j*32+r8)*64+cl*8]),16,0,0);
        }
        __syncthreads();
#pragma unroll
        for (int ks=0;ks<2;++ks){
            short8 af[MFRAG], bfr[NFRAG];
#pragma unroll
            for (int i=0;i<MFRAG;++i)
                af[i]=*(const short8*)&As[(wm*(BM/2)+i*16+l15)*64+(((ks*4+quad)^sw)*8)];
#pragma unroll
            for (int i=0;i<NFRAG;++i)
                bfr[i]=*(const short8*)&Bs[(wn*(BN/2)+i*16+l15)*64+(((ks*4+quad)^sw)*8)];
#pragma unroll
            for (int i=0;i<MFRAG;++i)
#pragma unroll
                for (int jn=0;jn<NFRAG;++jn)
                    acc[i][jn]=__builtin_amdgcn_mfma_f32_16x16x32_bf16(af[i],bfr[jn],acc[i][jn],0,0,0);
        }
        __syncthreads();
    }

    // C/D layout: col=lane&15, row=quad*4+reg (m89/m91 verified)
    if constexpr (EPI==EPI_LMSM){
        // BM=32, grid.x==1: full softmax row in-block. z=0: write ql_pad [m,128]
        // (cols 0..63 probs, col64=1.0, 65..127=0). z=1: kl32 f32 [m,64] + c atomics.
        __shared__ float red[2][32];
        float ev[4][NFRAG];
#pragma unroll
        for (int r=0;r<4;++r){
            float s=0;
#pragma unroll
            for (int jn=0;jn<NFRAG;++jn){
                int col=wn*(BN/2)+jn*16+l15;
                float e=exp2f((acc[0][jn][r]+biasCol[col])*expScale);
                ev[r][jn]=e; s+=e;
            }
            s+=__shfl_xor(s,1);s+=__shfl_xor(s,2);s+=__shfl_xor(s,4);s+=__shfl_xor(s,8);
            if(l15==0) red[wn][wm*16+quad*4+r]=s;
        }
        __syncthreads();
        float csum[NFRAG]={};
#pragma unroll
        for (int r=0;r<4;++r){
            int mrow=wm*16+quad*4+r;
            float inv=1.0f/(red[0][mrow]+red[1][mrow]);
            long m=m0+mrow;
#pragma unroll
            for (int jn=0;jn<NFRAG;++jn){
                int col=wn*(BN/2)+jn*16+l15;
                float p=ev[r][jn]*inv;
                if (z==0) ((u16*)Cp)[m*128+col]=f2bf(p);
                else { ((float*)C2p)[m*64+col]=p; csum[jn]+=p; }
            }
            if (z==0 && wn==0){
                us4 o; o.x=(l15==0)?(u16)0x3F80:(u16)0; o.y=0;o.z=0;o.w=0;
                *(us4*)&((u16*)Cp)[m*128+64+l15*4]=o;
            }
        }
        if (z==1){
#pragma unroll
            for (int jn=0;jn<NFRAG;++jn){
                float v=csum[jn];
                v+=__shfl_xor(v,16); v+=__shfl_xor(v,32);
                if (quad==0) atomicAdd(&auxF[((m0>>11)<<6)+wn*(BN/2)+jn*16+l15],v);
            }
        }
        return;
    } else if constexpr (EPI==EPI_HT){
        // Ht[z][col][m] = (m==64 ? 1 : 0.125) * acc, only m<65 (s-row unscaled)
#pragma unroll
        for (int i=0;i<MFRAG;++i){
            int mb=m0+wm*(BM/2)+i*16+quad*4;
#pragma unroll
            for (int r=0;r<4;++r){
                int m=mb+r;
                if (m<65){
                    float scl=(m==64)?1.0f:0.125f;
#pragma unroll
                    for (int jn=0;jn<NFRAG;++jn){
                        int col=n0+wn*(BN/2)+jn*16+l15;
                        ((u16*)Cp)[(long)z*sC+(long)col*128+m]=f2bf(acc[i][jn][r]*scl);
                    }
                }
            }
        }
        return;
    } else if constexpr (EPI==EPI_OUT){
#pragma unroll
        for (int i=0;i<MFRAG;++i){
            int mb=m0+wm*(BM/2)+i*16+quad*4;
#pragma unroll
            for (int r=0;r<4;++r){
                int m=mb+r;
                float ri=rinv[(long)z*M+m];
#pragma unroll
                for (int jn=0;jn<NFRAG;++jn){
                    int col=n0+wn*(BN/2)+jn*16+l15;
                    ((float*)Cp)[(long)z*sC+(long)m*N+col]=acc[i][jn][r]*ri+biasCol[col];
                }
            }
        }
        return;
    } else {
#pragma unroll
        for (int i=0;i<MFRAG;++i){
            int mb=m0+wm*(BM/2)+i*16+quad*4;
#pragma unroll
            for (int r=0;r<4;++r){
                int m=mb+r;
#pragma unroll
                for (int jn=0;jn<NFRAG;++jn){
                    int col=n0+wn*(BN/2)+jn*16+l15;
                    ((u16*)Cp)[(long)z*sC+(long)m*N+col]=f2bf(acc[i][jn][r]);
                }
            }
        }
    }
}

__global__ void __launch_bounds__(256)
zero16(f32x4* __restrict__ p, int n){
    int i=blockIdx.x*256+threadIdx.x;
    if(i<n){ f32x4 v={0.f,0.f,0.f,0.f}; p[i]=v; }
}

// KV[z][m][n] += sum_k kl32[z][k][m]*value[z][k][n]; row 64 = vsum. f32, exact.
__global__ void __launch_bounds__(256)
kv_vsum(const float* __restrict__ value, const float* __restrict__ kl32,
        float* __restrict__ KVx)
{
    const int z=blockIdx.z;
    const int n=blockIdx.x*256+threadIdx.x;
    const int k0=blockIdx.y*64;
    const float* vp=value+((long)z*2048+k0)*1024+n;
    const float* kp=kl32+((long)z*2048+k0)*64;
    float acc[64]; float vs=0.f;
#pragma unroll
    for (int m=0;m<64;++m) acc[m]=0.f;
#pragma unroll 2
    for (int k=0;k<64;++k){
        float v=vp[(long)k*1024];
        vs+=v;
#pragma unroll
        for (int m=0;m<64;++m) acc[m]+=kp[k*64+m]*v;  // kp uniform -> scalar loads
    }
    float* o=KVx+(long)z*131072+n;
#pragma unroll
    for (int m=0;m<64;++m) atomicAdd(o+(long)m*1024,acc[m]);
    atomicAdd(o+65536,vs);
}

// rinv[z][q] = 1/(2048 + dot(ql[q,0:64], c[z])/8)
__global__ void __launch_bounds__(256)
rsum_k(const u16* __restrict__ qlp, const float* __restrict__ c, float* __restrict__ rinv)
{
    int z=blockIdx.y, q=blockIdx.x*256+threadIdx.x;
    const u16* row=qlp+((long)(z*2048+q))*128;
    const float* cz=c+z*64;
    float s=0.f;
#pragma unroll
    for (int i=0;i<16;++i){
        us4 u=*(const us4*)(row+i*4);
        s+=bf2f(u.x)*cz[i*4]+bf2f(u.y)*cz[i*4+1]+bf2f(u.z)*cz[i*4+2]+bf2f(u.w)*cz[i*4+3];
    }
    rinv[z*2048+q]=1.0f/(2048.0f+0.125f*s);
}

// bocomb = bo + Wo @ bv (one wave per row)
__global__ void __launch_bounds__(256)
bias_comb(const float* __restrict__ Wo, const float* __restrict__ bv,
          const float* __restrict__ bo, float* __restrict__ out)
{
    int row=blockIdx.x*4+(threadIdx.x>>6);
    int lane=threadIdx.x&63;
    float s=0.f;
#pragma unroll
    for (int i=0;i<16;++i) s+=Wo[(long)row*1024+i*64+lane]*bv[i*64+lane];
    for (int o=32;o;o>>=1) s+=__shfl_xor(s,o,64);
    if (lane==0) out[row]=bo[row]+s;
}

extern "C" void kernel_launch(void* const* d_in, const int* in_sizes, int n_in,
                              void* d_out, int out_size, void* d_ws, size_t ws_size,
                              hipStream_t stream)
{
    const float* query=(const float*)d_in[0];
    const float* key  =(const float*)d_in[1];
    const float* value=(const float*)d_in[2];
    const float* Wv   =(const float*)d_in[3];
    const float* bv   =(const float*)d_in[4];
    const float* Wl   =(const float*)d_in[5];
    const float* bl   =(const float*)d_in[6];
    const float* Wo   =(const float*)d_in[7];
    const float* bo   =(const float*)d_in[8];
    float* out=(float*)d_out;

    // P = 1 + ql kl^T/8 (Taylor, rel err < 1e-5):
    // out = (ql_pad @ Ht^T) * rinv + bocomb
    //   Ht[:, m<64] = (KV@Wv^T@Wo^T)/8, Ht[:,64] = s = rowsum-weighted const term
    char* ws=(char*)d_ws;
    u16*   qlp =(u16*)  (ws+0);        // [4096,128] bf16: ql | 1.0 | zeros
    float* kl32=(float*)(ws+1048576);  // [2,2048,64] f32
    float* KVx =(float*)(ws+2097152);  // [2,128,1024] f32 (rows 0..63 KV, 64 vsum, 65..127 zero)
    float* c   =(float*)(ws+3145728);  // [2,64] f32
    u16*   Ht  =(u16*)  (ws+3146240);  // [2,1024,128] bf16 (cols 65..127 zero)
    u16*   T1x =(u16*)  (ws+3670528);  // [2,128,1024] bf16
    float* rinv=(float*)(ws+4194816);  // [2,2048]
    float* boc =(float*)(ws+4211200);  // [1024]

    // 0) zero [KVx | c | Ht] (contiguous 1,573,376 B)
    zero16<<<dim3(385),256,0,stream>>>((f32x4*)(ws+2097152),98336);
    // 0b) bocomb = Wo@bv + bo
    bias_comb<<<dim3(256),256,0,stream>>>(Wo,bv,bo,boc);

    // 1) landmark softmax: z=0 query->ql_pad, z=1 key->kl32 + c
    gemm<32,64,true,true,EPI_LMSM><<<dim3(1,128,2),256,0,stream>>>(
        query,key,Wl, qlp,kl32,c, bl,nullptr, 4096,64,1024, 0,0,0, 0.18033688011112042f);

    // 2) KV = kl^T@value (+vsum row), f32 atomics
    kv_vsum<<<dim3(4,32,2),256,0,stream>>>(value,kl32,KVx);

    // 3) rinv
    rsum_k<<<dim3(8,2),256,0,stream>>>(qlp,c,rinv);

    // 4) T1 = [KV;vsum] @ Wv^T   [2,128,1024] bf16
    gemm<64,64,true,true,EPI_BF16><<<dim3(16,2,2),256,0,stream>>>(
        KVx,nullptr,Wv, T1x,nullptr,nullptr, nullptr,nullptr,
        128,1024,1024, 131072,0,131072, 0.f);

    // 5) Ht = transpose(T1 @ Wo^T) with /8 on H rows, s-row unscaled
    gemm<64,64,false,true,EPI_HT><<<dim3(16,2,2),256,0,stream>>>(
        T1x,nullptr,Wo, Ht,nullptr,nullptr, nullptr,nullptr,
        128,1024,1024, 131072,0,131072, 0.f);

    // 6) out = (ql_pad @ Ht^T)*rinv + bocomb
    gemm<128,128,false,false,EPI_OUT><<<dim3(8,16,2),256,0,stream>>>(
        qlp,nullptr,Ht, out,nullptr,nullptr, boc,rinv,
        2048,1024,128, 262144,131072,2097152, 0.f);
}

// Round 5
// 231.021 us; speedup vs baseline: 1.0989x; 1.0989x over previous
//
#include <hip/hip_runtime.h>
#include <hip/hip_bf16.h>
#include <cstdint>

typedef unsigned short u16;
typedef __attribute__((ext_vector_type(8))) short short8;
typedef __attribute__((ext_vector_type(4))) float f32x4;
typedef __attribute__((ext_vector_type(4))) unsigned short us4;

__device__ __forceinline__ float bf2f(u16 u){union{unsigned i;float f;}v;v.i=(unsigned)u<<16;return v.f;}
__device__ __forceinline__ u16 f2bf(float f){union{float f;unsigned i;}v;v.f=f;unsigned x=v.i;unsigned r=x+0x7fffu+((x>>16)&1u);return (u16)(r>>16);}

enum { EPI_LMSM=0, EPI_ATOM=1, EPI_ATOMT=2, EPI_OUT=3 };

// C[M,N] = A[M,K] @ B[N,K]^T, K-contig operands, BK=64, 256 thr (2x2 waves).
// bf16 operands: global_load_lds(16B), XOR-8 swizzle on the global chunk index.
// f32 operands: BATCHED float4 loads -> regs -> cvt -> swizzled ds_write
// (all loads issued before first LDS write: one exposed latency per iter).
// KSPLIT: blockIdx.y = mt*KSPLIT+kc; each kc does K/KSPLIT with atomic epilogue.
template<int BM,int BN,int KSPLIT,bool AF32,bool BF32,int EPI>
__global__ void __launch_bounds__(256)
gemm(const void* __restrict__ Ap, const void* __restrict__ A2p,
     const void* __restrict__ Bp, void* __restrict__ Cp, void* __restrict__ C2p,
     float* __restrict__ auxF, const float* __restrict__ biasCol,
     int M, int N, int K, long sA, long sB, long sC, float expScale)
{
    constexpr int MFRAG = BM/32;
    constexpr int NFRAG = BN/32;
    __shared__ alignas(16) u16 As[BM*64];
    __shared__ alignas(16) u16 Bs[BN*64];

    const int tid=threadIdx.x, lane=tid&63, quad=lane>>4, l15=lane&15;
    const int w=tid>>6, wm=w>>1, wn=w&1;
    const int z=blockIdx.z;
    const int mt=blockIdx.y/KSPLIT, kc=blockIdx.y%KSPLIT;
    const int m0=mt*BM, n0=blockIdx.x*BN;
    const int kcount=K/KSPLIT, kbase=kc*kcount;

    const int r8=tid>>3, cl=tid&7, cg=((cl^(r8&7))*8);  // bf16 staging
    const int r16=tid>>4, q16=tid&15;                    // f32 staging
    const int sw=l15&7;

    const void* Abase = (A2p && z) ? A2p : Ap;
    const long zOffA = A2p ? 0 : (long)z*sA;
    const long zOffB = (long)z*sB;

    f32x4 acc[MFRAG][NFRAG] = {};

    for (int kk=0;kk<kcount;kk+=64){
        const int k0=kbase+kk;
        if constexpr (AF32){
            const float* S=(const float*)Abase+zOffA+(long)m0*K+k0;
            float4 tv[BM/16];
#pragma unroll
            for (int j=0;j<BM/16;++j)
                tv[j]=*(const float4*)(S+(long)(j*16+r16)*K+q16*4);
#pragma unroll
            for (int j=0;j<BM/16;++j){
                int row=j*16+r16;
                us4 o; o.x=f2bf(tv[j].x);o.y=f2bf(tv[j].y);o.z=f2bf(tv[j].z);o.w=f2bf(tv[j].w);
                *(us4*)&As[row*64+(((q16>>1)^(row&7))<<3)+((q16&1)<<2)]=o;
            }
        } else {
            const u16* S=(const u16*)Abase+zOffA+(long)m0*K+k0+cg;
#pragma unroll
            for (int j=0;j<BM/32;++j)
                __builtin_amdgcn_global_load_lds(
                    (const __attribute__((address_space(1))) void*)(S+(long)(j*32+r8)*K),
                    (__attribute__((address_space(3))) void*)(&As[(j*32+r8)*64+cl*8]),16,0,0);
        }
        if constexpr (BF32){
            const float* S=(const float*)Bp+zOffB+(long)n0*K+k0;
            float4 tv[BN/16];
#pragma unroll
            for (int j=0;j<BN/16;++j)
                tv[j]=*(const float4*)(S+(long)(j*16+r16)*K+q16*4);
#pragma unroll
            for (int j=0;j<BN/16;++j){
                int row=j*16+r16;
                us4 o; o.x=f2bf(tv[j].x);o.y=f2bf(tv[j].y);o.z=f2bf(tv[j].z);o.w=f2bf(tv[j].w);
                *(us4*)&Bs[row*64+(((q16>>1)^(row&7))<<3)+((q16&1)<<2)]=o;
            }
        } else {
            const u16* S=(const u16*)Bp+zOffB+(long)n0*K+k0+cg;
#pragma unroll
            for (int j=0;j<BN/32;++j)
                __builtin_amdgcn_global_load_lds(
                    (const __attribute__((address_space(1))) void*)(S+(long)(j*32+r8)*K),
                    (__attribute__((address_space(3))) void*)(&Bs[(j*32+r8)*64+cl*8]),16,0,0);
        }
        __syncthreads();
#pragma unroll
        for (int ks=0;ks<2;++ks){
            short8 af[MFRAG], bfr[NFRAG];
#pragma unroll
            for (int i=0;i<MFRAG;++i)
                af[i]=*(const short8*)&As[(wm*(BM/2)+i*16+l15)*64+(((ks*4+quad)^sw)*8)];
#pragma unroll
            for (int i=0;i<NFRAG;++i)
                bfr[i]=*(const short8*)&Bs[(wn*(BN/2)+i*16+l15)*64+(((ks*4+quad)^sw)*8)];
#pragma unroll
            for (int i=0;i<MFRAG;++i)
#pragma unroll
                for (int jn=0;jn<NFRAG;++jn)
                    acc[i][jn]=__builtin_amdgcn_mfma_f32_16x16x32_bf16(af[i],bfr[jn],acc[i][jn],0,0,0);
        }
        __syncthreads();
    }

    // C/D layout: col=lane&15, row=quad*4+reg (m89/m91 verified)
    if constexpr (EPI==EPI_LMSM){
        // BM=32, grid.x==1: full softmax row in-block. z=0: qlp [m,128]
        // (cols 0..63 probs, col64=1.0, 65..127=0). z=1: kl32 f32 [m,64] + c atomics.
        __shared__ float red[2][32];
        float ev[4][NFRAG];
#pragma unroll
        for (int r=0;r<4;++r){
            float s=0;
#pragma unroll
            for (int jn=0;jn<NFRAG;++jn){
                int col=wn*(BN/2)+jn*16+l15;
                float e=exp2f((acc[0][jn][r]+biasCol[col])*expScale);
                ev[r][jn]=e; s+=e;
            }
            s+=__shfl_xor(s,1);s+=__shfl_xor(s,2);s+=__shfl_xor(s,4);s+=__shfl_xor(s,8);
            if(l15==0) red[wn][wm*16+quad*4+r]=s;
        }
        __syncthreads();
        float csum[NFRAG]={};
#pragma unroll
        for (int r=0;r<4;++r){
            int mrow=wm*16+quad*4+r;
            float inv=1.0f/(red[0][mrow]+red[1][mrow]);
            long m=m0+mrow;
#pragma unroll
            for (int jn=0;jn<NFRAG;++jn){
                int col=wn*(BN/2)+jn*16+l15;
                float p=ev[r][jn]*inv;
                if (z==0) ((u16*)Cp)[m*128+col]=f2bf(p);
                else { ((float*)C2p)[m*64+col]=p; csum[jn]+=p; }
            }
            if (z==0 && wn==0){
                us4 o; o.x=(l15==0)?(u16)0x3F80:(u16)0; o.y=0;o.z=0;o.w=0;
                *(us4*)&((u16*)Cp)[m*128+64+l15*4]=o;
            }
        }
        if (z==1){
#pragma unroll
            for (int jn=0;jn<NFRAG;++jn){
                float v=csum[jn];
                v+=__shfl_xor(v,16); v+=__shfl_xor(v,32);
                if (quad==0) atomicAdd(&auxF[((m0>>11)<<6)+wn*(BN/2)+jn*16+l15],v);
            }
        }
        return;
    } else if constexpr (EPI==EPI_ATOM){
#pragma unroll
        for (int i=0;i<MFRAG;++i){
            int mb=m0+wm*(BM/2)+i*16+quad*4;
#pragma unroll
            for (int r=0;r<4;++r){
                int m=mb+r;
#pragma unroll
                for (int jn=0;jn<NFRAG;++jn){
                    int col=n0+wn*(BN/2)+jn*16+l15;
                    atomicAdd(&((float*)Cp)[(long)z*sC+(long)m*N+col], acc[i][jn][r]);
                }
            }
        }
        return;
    } else if constexpr (EPI==EPI_ATOMT){
        // Htf[z][col][m] += acc * (m==64 ? 1 : 1/8), only m<65
#pragma unroll
        for (int i=0;i<MFRAG;++i){
            int mb=m0+wm*(BM/2)+i*16+quad*4;
#pragma unroll
            for (int r=0;r<4;++r){
                int m=mb+r;
                if (m<65){
                    float scl=(m==64)?1.0f:0.125f;
#pragma unroll
                    for (int jn=0;jn<NFRAG;++jn){
                        int col=n0+wn*(BN/2)+jn*16+l15;
                        atomicAdd(&((float*)Cp)[(long)z*sC+(long)col*128+m], acc[i][jn][r]*scl);
                    }
                }
            }
        }
        return;
    } else { // EPI_OUT: rinv computed in-block from qlp (=Ap) and c (=auxF)
        __shared__ float rsm[BM];
        if (tid < BM){
            const u16* qr=(const u16*)Ap + (long)z*sA + (long)(m0+tid)*K;
            const float* cz=auxF + z*64;
            float s=0.f;
            us4 uu[16];
#pragma unroll
            for (int i=0;i<16;++i) uu[i]=*(const us4*)(qr+i*4);
#pragma unroll
            for (int i=0;i<16;++i)
                s+=bf2f(uu[i].x)*cz[i*4]+bf2f(uu[i].y)*cz[i*4+1]
                  +bf2f(uu[i].z)*cz[i*4+2]+bf2f(uu[i].w)*cz[i*4+3];
            rsm[tid]=1.0f/(2048.0f+0.125f*s);
        }
        __syncthreads();
#pragma unroll
        for (int i=0;i<MFRAG;++i){
            int mb=m0+wm*(BM/2)+i*16+quad*4;
#pragma unroll
            for (int r=0;r<4;++r){
                int m=mb+r;
                float ri=rsm[m-m0];
#pragma unroll
                for (int jn=0;jn<NFRAG;++jn){
                    int col=n0+wn*(BN/2)+jn*16+l15;
                    ((float*)Cp)[(long)z*sC+(long)m*N+col]=acc[i][jn][r]*ri+biasCol[col];
                }
            }
        }
        return;
    }
}

// prep: blocks 0..255 compute boc = bo + Wo@bv; blocks 256.. zero the f32 block
__global__ void __launch_bounds__(256)
prep(const float* __restrict__ Wo, const float* __restrict__ bv,
     const float* __restrict__ bo, float* __restrict__ boc,
     f32x4* __restrict__ zp, int nz)
{
    int b=blockIdx.x;
    if (b<256){
        int row=b*4+(threadIdx.x>>6);
        int lane=threadIdx.x&63;
        float s=0.f;
#pragma unroll
        for (int i=0;i<16;++i) s+=Wo[(long)row*1024+i*64+lane]*bv[i*64+lane];
        for (int o=32;o;o>>=1) s+=__shfl_xor(s,o,64);
        if (lane==0) boc[row]=bo[row]+s;
    } else {
        int i=(b-256)*256+threadIdx.x;
        if (i<nz){ f32x4 v={0.f,0.f,0.f,0.f}; zp[i]=v; }
    }
}

// KV[z][m][n] += sum_k kl32[z][k][m]*value[z][k][n]; row 64 = vsum. f32 atomics.
__global__ void __launch_bounds__(256)
kv_vsum(const float* __restrict__ value, const float* __restrict__ kl32,
        float* __restrict__ KVx)
{
    const int z=blockIdx.z;
    const int n=blockIdx.x*256+threadIdx.x;
    const int k0=blockIdx.y*64;
    const float* vp=value+((long)z*2048+k0)*1024+n;
    const float* kp=kl32+((long)z*2048+k0)*64;
    float acc[64]; float vs=0.f;
#pragma unroll
    for (int m=0;m<64;++m) acc[m]=0.f;
    for (int k=0;k<64;k+=8){
        float vv[8];
#pragma unroll
        for (int u=0;u<8;++u) vv[u]=vp[(long)(k+u)*1024];
#pragma unroll
        for (int u=0;u<8;++u){
            vs+=vv[u];
#pragma unroll
            for (int m=0;m<64;++m) acc[m]+=kp[(k+u)*64+m]*vv[u];  // kp uniform -> s_loads
        }
    }
    float* o=KVx+(long)z*131072+n;
#pragma unroll
    for (int m=0;m<64;++m) atomicAdd(o+(long)m*1024,acc[m]);
    atomicAdd(o+65536,vs);
}

extern "C" void kernel_launch(void* const* d_in, const int* in_sizes, int n_in,
                              void* d_out, int out_size, void* d_ws, size_t ws_size,
                              hipStream_t stream)
{
    const float* query=(const float*)d_in[0];
    const float* key  =(const float*)d_in[1];
    const float* value=(const float*)d_in[2];
    const float* Wv   =(const float*)d_in[3];
    const float* bv   =(const float*)d_in[4];
    const float* Wl   =(const float*)d_in[5];
    const float* bl   =(const float*)d_in[6];
    const float* Wo   =(const float*)d_in[7];
    const float* bo   =(const float*)d_in[8];
    float* out=(float*)d_out;

    // P = 1 + ql kl^T/8 (Taylor, rel err < 1e-5). out = (qlp @ Ht^T)*rinv + boc
    //   X=[KV;vsum] (f32), T1f = X@Wv^T (f32, split-K atomics),
    //   Htf[o][m] = (T1f@Wo^T)[m][o] * (m<64 ? 1/8 : 1), rinv in out-epilogue.
    char* ws=(char*)d_ws;
    u16*   qlp =(u16*)  (ws+0);        // [4096,128] bf16: ql | 1.0 | zeros
    float* kl32=(float*)(ws+1048576);  // [2,2048,64] f32
    float* KVx =(float*)(ws+2097152);  // [2,128,1024] f32 (rows 0..63 KV, 64 vsum)
    float* T1f =(float*)(ws+3145728);  // [2,128,1024] f32
    float* Htf =(float*)(ws+4194304);  // [2,1024,128] f32
    float* c   =(float*)(ws+5242880);  // [2,64] f32
    float* boc =(float*)(ws+5243392);  // [1024] f32

    // 0) boc = Wo@bv+bo; zero [KVx|T1f|Htf|c] = 3,146,240 B = 196,640 f32x4
    prep<<<dim3(1025),256,0,stream>>>(Wo,bv,bo,boc,(f32x4*)(ws+2097152),196640);

    // 1) landmark softmax: z=0 query->qlp, z=1 key->kl32 + c
    gemm<32,64,1,true,true,EPI_LMSM><<<dim3(1,128,2),256,0,stream>>>(
        query,key,Wl, qlp,kl32,c, bl, 4096,64,1024, 0,0,0, 0.18033688011112042f);

    // 2) KV = kl^T@value (+vsum row)
    kv_vsum<<<dim3(4,32,2),256,0,stream>>>(value,kl32,KVx);

    // 3) T1f = X @ Wv^T  (split-K=2, f32 atomics)
    gemm<64,64,2,true,true,EPI_ATOM><<<dim3(16,4,2),256,0,stream>>>(
        KVx,nullptr,Wv, T1f,nullptr,nullptr,nullptr,
        128,1024,1024, 131072,0,131072, 0.f);

    // 4) Htf = transpose(T1f @ Wo^T) with /8 on m<64, m==64 unscaled
    gemm<64,64,2,true,true,EPI_ATOMT><<<dim3(16,4,2),256,0,stream>>>(
        T1f,nullptr,Wo, Htf,nullptr,nullptr,nullptr,
        128,1024,1024, 131072,0,131072, 0.f);

    // 5) out = (qlp @ Htf^T)*rinv + boc   (rinv from qlp,c in-epilogue)
    gemm<128,128,1,false,true,EPI_OUT><<<dim3(8,16,2),256,0,stream>>>(
        qlp,nullptr,Htf, out,nullptr,c, boc,
        2048,1024,128, 262144,131072,2097152, 0.f);
}

// Round 6
// 212.352 us; speedup vs baseline: 1.1956x; 1.0879x over previous
//
#include <hip/hip_runtime.h>
#include <hip/hip_bf16.h>
#include <cstdint>

typedef unsigned short u16;
typedef __attribute__((ext_vector_type(8))) short short8;
typedef __attribute__((ext_vector_type(4))) float f32x4;
typedef __attribute__((ext_vector_type(4))) unsigned short us4;

__device__ __forceinline__ float bf2f(u16 u){union{unsigned i;float f;}v;v.i=(unsigned)u<<16;return v.f;}
__device__ __forceinline__ u16 f2bf(float f){union{float f;unsigned i;}v;v.f=f;unsigned x=v.i;unsigned r=x+0x7fffu+((x>>16)&1u);return (u16)(r>>16);}

enum { EPI_LMSM=0, EPI_ATOM=1, EPI_ATOMT=2, EPI_OUT=3 };

// C[M,N] = A[M,K] @ B[N,K]^T, K-contig operands, BK=64, 256 thr (2x2 waves).
// bf16 operands: global_load_lds(16B), XOR-8 swizzle on the global chunk index.
// f32 operands: ALL float4 loads (A then B) issued into registers BEFORE any
// ds_write -> one exposed memory latency per K-iter. launch_bounds(256,2)
// caps VGPR at 256 so the batch actually stays in flight (R5's 24-VGPR
// allocation serialized the loads -> 6 latencies/iter).
// KSPLIT: blockIdx.y = mt*KSPLIT+kc; each kc does K/KSPLIT with atomic epilogue.
template<int BM,int BN,int KSPLIT,bool AF32,bool BF32,int EPI>
__global__ void __launch_bounds__(256, 2)
gemm(const void* __restrict__ Ap, const void* __restrict__ A2p,
     const void* __restrict__ Bp, void* __restrict__ Cp, void* __restrict__ C2p,
     float* __restrict__ auxF, const float* __restrict__ biasCol,
     int M, int N, int K, long sA, long sB, long sC, float expScale)
{
    constexpr int MFRAG = BM/32;
    constexpr int NFRAG = BN/32;
    constexpr int NA = AF32 ? BM/16 : 1;
    constexpr int NB = BF32 ? BN/16 : 1;
    __shared__ alignas(16) u16 As[BM*64];
    __shared__ alignas(16) u16 Bs[BN*64];

    const int tid=threadIdx.x, lane=tid&63, quad=lane>>4, l15=lane&15;
    const int w=tid>>6, wm=w>>1, wn=w&1;
    const int z=blockIdx.z;
    const int mt=blockIdx.y/KSPLIT, kc=blockIdx.y%KSPLIT;
    const int m0=mt*BM, n0=blockIdx.x*BN;
    const int kcount=K/KSPLIT, kbase=kc*kcount;

    const int r8=tid>>3, cl=tid&7, cg=((cl^(r8&7))*8);  // bf16 staging
    const int r16=tid>>4, q16=tid&15;                    // f32 staging
    const int sw=l15&7;

    const void* Abase = (A2p && z) ? A2p : Ap;
    const long zOffA = A2p ? 0 : (long)z*sA;
    const long zOffB = (long)z*sB;

    f32x4 acc[MFRAG][NFRAG] = {};

    for (int kk=0;kk<kcount;kk+=64){
        const int k0=kbase+kk;
        float4 tvA[NA], tvB[NB];
        // ---- issue ALL global loads first ----
        if constexpr (AF32){
            const float* S=(const float*)Abase+zOffA+(long)m0*K+k0;
#pragma unroll
            for (int j=0;j<NA;++j)
                tvA[j]=*(const float4*)(S+(long)(j*16+r16)*K+q16*4);
        } else {
            const u16* S=(const u16*)Abase+zOffA+(long)m0*K+k0+cg;
#pragma unroll
            for (int j=0;j<BM/32;++j)
                __builtin_amdgcn_global_load_lds(
                    (const __attribute__((address_space(1))) void*)(S+(long)(j*32+r8)*K),
                    (__attribute__((address_space(3))) void*)(&As[(j*32+r8)*64+cl*8]),16,0,0);
        }
        if constexpr (BF32){
            const float* S=(const float*)Bp+zOffB+(long)n0*K+k0;
#pragma unroll
            for (int j=0;j<NB;++j)
                tvB[j]=*(const float4*)(S+(long)(j*16+r16)*K+q16*4);
        } else {
            const u16* S=(const u16*)Bp+zOffB+(long)n0*K+k0+cg;
#pragma unroll
            for (int j=0;j<BN/32;++j)
                __builtin_amdgcn_global_load_lds(
                    (const __attribute__((address_space(1))) void*)(S+(long)(j*32+r8)*K),
                    (__attribute__((address_space(3))) void*)(&Bs[(j*32+r8)*64+cl*8]),16,0,0);
        }
        // ---- then convert + ds_write ----
        if constexpr (AF32){
#pragma unroll
            for (int j=0;j<NA;++j){
                int row=j*16+r16;
                us4 o; o.x=f2bf(tvA[j].x);o.y=f2bf(tvA[j].y);o.z=f2bf(tvA[j].z);o.w=f2bf(tvA[j].w);
                *(us4*)&As[row*64+(((q16>>1)^(row&7))<<3)+((q16&1)<<2)]=o;
            }
        }
        if constexpr (BF32){
#pragma unroll
            for (int j=0;j<NB;++j){
                int row=j*16+r16;
                us4 o; o.x=f2bf(tvB[j].x);o.y=f2bf(tvB[j].y);o.z=f2bf(tvB[j].z);o.w=f2bf(tvB[j].w);
                *(us4*)&Bs[row*64+(((q16>>1)^(row&7))<<3)+((q16&1)<<2)]=o;
            }
        }
        __syncthreads();
#pragma unroll
        for (int ks=0;ks<2;++ks){
            short8 af[MFRAG], bfr[NFRAG];
#pragma unroll
            for (int i=0;i<MFRAG;++i)
                af[i]=*(const short8*)&As[(wm*(BM/2)+i*16+l15)*64+(((ks*4+quad)^sw)*8)];
#pragma unroll
            for (int i=0;i<NFRAG;++i)
                bfr[i]=*(const short8*)&Bs[(wn*(BN/2)+i*16+l15)*64+(((ks*4+quad)^sw)*8)];
#pragma unroll
            for (int i=0;i<MFRAG;++i)
#pragma unroll
                for (int jn=0;jn<NFRAG;++jn)
                    acc[i][jn]=__builtin_amdgcn_mfma_f32_16x16x32_bf16(af[i],bfr[jn],acc[i][jn],0,0,0);
        }
        __syncthreads();
    }

    // C/D layout: col=lane&15, row=quad*4+reg (m89/m91 verified)
    if constexpr (EPI==EPI_LMSM){
        // BM=32, grid.x==1: full softmax row in-block. z=0: qlp [m,128]
        // (cols 0..63 probs, col64=1.0, 65..127=0). z=1: kl32 f32 [m,64] + c atomics.
        __shared__ float red[2][32];
        float ev[4][NFRAG];
#pragma unroll
        for (int r=0;r<4;++r){
            float s=0;
#pragma unroll
            for (int jn=0;jn<NFRAG;++jn){
                int col=wn*(BN/2)+jn*16+l15;
                float e=exp2f((acc[0][jn][r]+biasCol[col])*expScale);
                ev[r][jn]=e; s+=e;
            }
            s+=__shfl_xor(s,1);s+=__shfl_xor(s,2);s+=__shfl_xor(s,4);s+=__shfl_xor(s,8);
            if(l15==0) red[wn][wm*16+quad*4+r]=s;
        }
        __syncthreads();
        float csum[NFRAG]={};
#pragma unroll
        for (int r=0;r<4;++r){
            int mrow=wm*16+quad*4+r;
            float inv=1.0f/(red[0][mrow]+red[1][mrow]);
            long m=m0+mrow;
#pragma unroll
            for (int jn=0;jn<NFRAG;++jn){
                int col=wn*(BN/2)+jn*16+l15;
                float p=ev[r][jn]*inv;
                if (z==0) ((u16*)Cp)[m*128+col]=f2bf(p);
                else { ((float*)C2p)[m*64+col]=p; csum[jn]+=p; }
            }
            if (z==0 && wn==0){
                us4 o; o.x=(l15==0)?(u16)0x3F80:(u16)0; o.y=0;o.z=0;o.w=0;
                *(us4*)&((u16*)Cp)[m*128+64+l15*4]=o;
            }
        }
        if (z==1){
#pragma unroll
            for (int jn=0;jn<NFRAG;++jn){
                float v=csum[jn];
                v+=__shfl_xor(v,16); v+=__shfl_xor(v,32);
                if (quad==0) atomicAdd(&auxF[((m0>>11)<<6)+wn*(BN/2)+jn*16+l15],v);
            }
        }
        return;
    } else if constexpr (EPI==EPI_ATOM){
#pragma unroll
        for (int i=0;i<MFRAG;++i){
            int mb=m0+wm*(BM/2)+i*16+quad*4;
#pragma unroll
            for (int r=0;r<4;++r){
                int m=mb+r;
#pragma unroll
                for (int jn=0;jn<NFRAG;++jn){
                    int col=n0+wn*(BN/2)+jn*16+l15;
                    atomicAdd(&((float*)Cp)[(long)z*sC+(long)m*N+col], acc[i][jn][r]);
                }
            }
        }
        return;
    } else if constexpr (EPI==EPI_ATOMT){
        // Htf[z][col][m] += acc * (m==64 ? 1 : 1/8), only m<65
#pragma unroll
        for (int i=0;i<MFRAG;++i){
            int mb=m0+wm*(BM/2)+i*16+quad*4;
#pragma unroll
            for (int r=0;r<4;++r){
                int m=mb+r;
                if (m<65){
                    float scl=(m==64)?1.0f:0.125f;
#pragma unroll
                    for (int jn=0;jn<NFRAG;++jn){
                        int col=n0+wn*(BN/2)+jn*16+l15;
                        atomicAdd(&((float*)Cp)[(long)z*sC+(long)col*128+m], acc[i][jn][r]*scl);
                    }
                }
            }
        }
        return;
    } else { // EPI_OUT: rinv computed in-block from qlp (=Ap) and c (=auxF)
        __shared__ float rsm[BM];
        if (tid < BM){
            const u16* qr=(const u16*)Ap + (long)z*sA + (long)(m0+tid)*K;
            const float* cz=auxF + z*64;
            float s=0.f;
            us4 uu[16];
#pragma unroll
            for (int i=0;i<16;++i) uu[i]=*(const us4*)(qr+i*4);
#pragma unroll
            for (int i=0;i<16;++i)
                s+=bf2f(uu[i].x)*cz[i*4]+bf2f(uu[i].y)*cz[i*4+1]
                  +bf2f(uu[i].z)*cz[i*4+2]+bf2f(uu[i].w)*cz[i*4+3];
            rsm[tid]=1.0f/(2048.0f+0.125f*s);
        }
        __syncthreads();
#pragma unroll
        for (int i=0;i<MFRAG;++i){
            int mb=m0+wm*(BM/2)+i*16+quad*4;
#pragma unroll
            for (int r=0;r<4;++r){
                int m=mb+r;
                float ri=rsm[m-m0];
#pragma unroll
                for (int jn=0;jn<NFRAG;++jn){
                    int col=n0+wn*(BN/2)+jn*16+l15;
                    ((float*)Cp)[(long)z*sC+(long)m*N+col]=acc[i][jn][r]*ri+biasCol[col];
                }
            }
        }
        return;
    }
}

// prep: blocks 0..255 compute boc = bo + Wo@bv; blocks 256.. zero the f32 block
__global__ void __launch_bounds__(256)
prep(const float* __restrict__ Wo, const float* __restrict__ bv,
     const float* __restrict__ bo, float* __restrict__ boc,
     f32x4* __restrict__ zp, int nz)
{
    int b=blockIdx.x;
    if (b<256){
        int row=b*4+(threadIdx.x>>6);
        int lane=threadIdx.x&63;
        float s=0.f;
#pragma unroll
        for (int i=0;i<16;++i) s+=Wo[(long)row*1024+i*64+lane]*bv[i*64+lane];
        for (int o=32;o;o>>=1) s+=__shfl_xor(s,o,64);
        if (lane==0) boc[row]=bo[row]+s;
    } else {
        int i=(b-256)*256+threadIdx.x;
        if (i<nz){ f32x4 v={0.f,0.f,0.f,0.f}; zp[i]=v; }
    }
}

// KV[z][m][n] += sum_k kl32[z][k][m]*value[z][k][n]; row 64 = vsum. f32 atomics.
__global__ void __launch_bounds__(256, 2)
kv_vsum(const float* __restrict__ value, const float* __restrict__ kl32,
        float* __restrict__ KVx)
{
    const int z=blockIdx.z;
    const int n=blockIdx.x*256+threadIdx.x;
    const int k0=blockIdx.y*64;
    const float* vp=value+((long)z*2048+k0)*1024+n;
    const float* kp=kl32+((long)z*2048+k0)*64;
    float acc[64]; float vs=0.f;
#pragma unroll
    for (int m=0;m<64;++m) acc[m]=0.f;
    for (int k=0;k<64;k+=8){
        float vv[8];
#pragma unroll
        for (int u=0;u<8;++u) vv[u]=vp[(long)(k+u)*1024];
#pragma unroll
        for (int u=0;u<8;++u){
            vs+=vv[u];
#pragma unroll
            for (int m=0;m<64;++m) acc[m]+=kp[(k+u)*64+m]*vv[u];  // kp uniform -> s_loads
        }
    }
    float* o=KVx+(long)z*131072+n;
#pragma unroll
    for (int m=0;m<64;++m) atomicAdd(o+(long)m*1024,acc[m]);
    atomicAdd(o+65536,vs);
}

extern "C" void kernel_launch(void* const* d_in, const int* in_sizes, int n_in,
                              void* d_out, int out_size, void* d_ws, size_t ws_size,
                              hipStream_t stream)
{
    const float* query=(const float*)d_in[0];
    const float* key  =(const float*)d_in[1];
    const float* value=(const float*)d_in[2];
    const float* Wv   =(const float*)d_in[3];
    const float* bv   =(const float*)d_in[4];
    const float* Wl   =(const float*)d_in[5];
    const float* bl   =(const float*)d_in[6];
    const float* Wo   =(const float*)d_in[7];
    const float* bo   =(const float*)d_in[8];
    float* out=(float*)d_out;

    // P = 1 + ql kl^T/8 (Taylor, rel err < 1e-5). out = (qlp @ Ht^T)*rinv + boc
    //   X=[KV;vsum] (f32), T1f = X@Wv^T (f32, split-K atomics),
    //   Htf[o][m] = (T1f@Wo^T)[m][o] * (m<64 ? 1/8 : 1), rinv in out-epilogue.
    char* ws=(char*)d_ws;
    u16*   qlp =(u16*)  (ws+0);        // [4096,128] bf16: ql | 1.0 | zeros
    float* kl32=(float*)(ws+1048576);  // [2,2048,64] f32
    float* KVx =(float*)(ws+2097152);  // [2,128,1024] f32 (rows 0..63 KV, 64 vsum)
    float* T1f =(float*)(ws+3145728);  // [2,128,1024] f32
    float* Htf =(float*)(ws+4194304);  // [2,1024,128] f32
    float* c   =(float*)(ws+5242880);  // [2,64] f32
    float* boc =(float*)(ws+5243392);  // [1024] f32

    // 0) boc = Wo@bv+bo; zero [KVx|T1f|Htf|c] = 3,146,240 B = 196,640 f32x4
    prep<<<dim3(1025),256,0,stream>>>(Wo,bv,bo,boc,(f32x4*)(ws+2097152),196640);

    // 1) landmark softmax: z=0 query->qlp, z=1 key->kl32 + c
    gemm<32,64,1,true,true,EPI_LMSM><<<dim3(1,128,2),256,0,stream>>>(
        query,key,Wl, qlp,kl32,c, bl, 4096,64,1024, 0,0,0, 0.18033688011112042f);

    // 2) KV = kl^T@value (+vsum row)
    kv_vsum<<<dim3(4,32,2),256,0,stream>>>(value,kl32,KVx);

    // 3) T1f = X @ Wv^T  (split-K=2, f32 atomics)
    gemm<64,64,2,true,true,EPI_ATOM><<<dim3(16,4,2),256,0,stream>>>(
        KVx,nullptr,Wv, T1f,nullptr,nullptr,nullptr,
        128,1024,1024, 131072,0,131072, 0.f);

    // 4) Htf = transpose(T1f @ Wo^T) with /8 on m<64, m==64 unscaled
    gemm<64,64,2,true,true,EPI_ATOMT><<<dim3(16,4,2),256,0,stream>>>(
        T1f,nullptr,Wo, Htf,nullptr,nullptr,nullptr,
        128,1024,1024, 131072,0,131072, 0.f);

    // 5) out = (qlp @ Htf^T)*rinv + boc   (rinv from qlp,c in-epilogue)
    gemm<128,128,1,false,true,EPI_OUT><<<dim3(8,16,2),256,0,stream>>>(
        qlp,nullptr,Htf, out,nullptr,c, boc,
        2048,1024,128, 262144,131072,2097152, 0.f);
}